// Round 2
// baseline (159.216 us; speedup 1.0000x reference)
//
#include <hip/hip_runtime.h>

typedef __attribute__((ext_vector_type(8))) _Float16 f16x8;
typedef __attribute__((ext_vector_type(4))) float   f32x4;

namespace {
constexpr int kB    = 8192;
constexpr int kTH   = 11;
constexpr int kTP   = 80;
constexpr int kM    = 16;    // batch rows per tile (MFMA M)
constexpr int kStrH = 72;    // H-plane row stride in fp16 units (144 B: 16B-aligned)
constexpr int kPB   = kM * kTP * 2;   // predbuf floats per tile
}

// 8 fp32 -> fp16x8 (round-to-nearest)
__device__ __forceinline__ f16x8 cvt8(const float* f) {
    f16x8 v;
#pragma unroll
    for (int j = 0; j < 8; ++j) v[j] = (_Float16)f[j];
    return v;
}

// B-fragment (single fp16) for column `col`: B[k][col] = W[col][k].
__device__ __forceinline__ void loadB1(const float* __restrict__ W, int col, int q,
                                       f16x8 (&Bf)[2]) {
#pragma unroll
    for (int c = 0; c < 2; ++c) {
        const float* src = W + col * 64 + c * 32 + q * 8;
        const float4 a = reinterpret_cast<const float4*>(src)[0];
        const float4 b = reinterpret_cast<const float4*>(src)[1];
        float f[8] = {a.x, a.y, a.z, a.w, b.x, b.y, b.z, b.w};
        Bf[c] = cvt8(f);
    }
}

// fc B-fragment: only cols p<2 are real (fcW is 2x64); others zero.
__device__ __forceinline__ void loadBfc(const float* __restrict__ fcW, int p, int q,
                                        f16x8 (&Bf)[2]) {
#pragma unroll
    for (int c = 0; c < 2; ++c) {
        float f[8];
#pragma unroll
        for (int j = 0; j < 8; ++j)
            f[j] = (p < 2) ? fcW[p * 64 + c * 32 + q * 8 + j] : 0.f;
        Bf[c] = cvt8(f);
    }
}

// G = w0 (x) fcW[0] + w1 (x) fcW[1]  (rank-2 folded feedback matrix)
__device__ __forceinline__ void loadBG(const float* __restrict__ fcW, float w0, float w1,
                                       int q, f16x8 (&Bf)[2]) {
#pragma unroll
    for (int c = 0; c < 2; ++c) {
        float f[8];
#pragma unroll
        for (int j = 0; j < 8; ++j) {
            const int k = c * 32 + q * 8 + j;
            f[j] = w0 * fcW[k] + w1 * fcW[64 + k];
        }
        Bf[c] = cvt8(f);
    }
}

__device__ __forceinline__ f16x8 read_frag(const _Float16* plane, int off) {
    return *reinterpret_cast<const f16x8*>(plane + off);
}

// single-term accumulate: D += A*B (A = fp16 h, B = fp16 W)
__device__ __forceinline__ f32x4 mfma1(f16x8 a, f16x8 b, f32x4 acc) {
    return __builtin_amdgcn_mfma_f32_16x16x32_f16(a, b, acc, 0, 0, 0);
}

// tanh via raw v_exp/v_rcp: 1 - 2*rcp(2^(2*log2e*x)+1); saturates safely.
__device__ __forceinline__ float fast_tanh(float x) {
    const float e = __builtin_amdgcn_exp2f(x * 2.8853900817779268f);  // 2/ln2
    return fmaf(-2.0f, __builtin_amdgcn_rcpf(e + 1.0f), 1.0f);
}

// R11 structure: 256 blocks x 4 waves (n-split) x 2 batch tiles (a,b) per block.
// 1 block/CU: latency hiding is explicit 2-tile ILP via fully hand-named
// fragments (no register arrays, no branches around MFMAs). Barriers serve
// 32 rows each; per-tile statement sequence is identical to the proven R9.
__global__ __attribute__((amdgpu_waves_per_eu(2, 2))) __launch_bounds__(256)
void traj_rnn_kernel(
    const float* __restrict__ x,
    const float* __restrict__ eWih0, const float* __restrict__ eWhh0,
    const float* __restrict__ ebih0, const float* __restrict__ ebhh0,
    const float* __restrict__ eWih1, const float* __restrict__ eWhh1,
    const float* __restrict__ ebih1, const float* __restrict__ ebhh1,
    const float* __restrict__ dWih0, const float* __restrict__ dWhh0,
    const float* __restrict__ dbih0, const float* __restrict__ dbhh0,
    const float* __restrict__ dWih1, const float* __restrict__ dWhh1,
    const float* __restrict__ dbih1, const float* __restrict__ dbhh1,
    const float* __restrict__ fcW, const float* __restrict__ fcb,
    float* __restrict__ out)
{
    const int tid  = threadIdx.x;
    const int wv   = tid >> 6;          // n-tile owned by this wave (0..3)
    const int lane = tid & 63;
    const int p    = lane & 15;         // A-m / C-col-within-tile
    const int q    = lane >> 4;         // k-quad / C row-quad
    const int col  = wv * 16 + p;       // this lane's hidden-unit column
    const int r0   = blockIdx.x * (2 * kM);

    __shared__ __align__(16) _Float16 Hhi1a[kM * kStrH];
    __shared__ __align__(16) _Float16 Hhi1b[kM * kStrH];
    __shared__ __align__(16) _Float16 Hhi2a[kM * kStrH];
    __shared__ __align__(16) _Float16 Hhi2b[kM * kStrH];
    __shared__ __align__(16) float xbuf[2 * kM * kTH * 2];
    __shared__ __align__(16) float predbuf[2 * kPB];   // [tile a | tile b]

    for (int i = tid; i < 2 * kM * kTH * 2; i += 256)
        xbuf[i] = x[r0 * (kTH * 2) + i];

    const float* xbufA = xbuf;                       // rows r0   .. r0+15
    const float* xbufB = xbuf + kM * kTH * 2;        // rows r0+16.. r0+31

    const f16x8 Z = {0, 0, 0, 0, 0, 0, 0, 0};
    f16x8 H1a0 = Z, H1a1 = Z, H1b0 = Z, H1b1 = Z;    // layer-1 A-fragments
    f16x8 H2a0 = Z, H2a1 = Z, H2b0 = Z, H2b1 = Z;    // layer-2 A-fragments
    __syncthreads();

    const int aoff = p * kStrH;  // A-fragment base for this lane's m-row

    // ================= encoder: 11 steps =================
    f32x4 P1a, P1b;
    {
        const float b0 = ebih0[col] + ebhh0[col];
        const float b1 = ebih1[col] + ebhh1[col];
        const float w0 = eWih0[col * 2 + 0];
        const float w1 = eWih0[col * 2 + 1];
        f16x8 B0[2], B1[2], B2[2];
        loadB1(eWhh0, col, q, B0);   // Whh0
        loadB1(eWih1, col, q, B1);   // Wih1
        loadB1(eWhh1, col, q, B2);   // Whh1

        P1a = f32x4{b0, b0, b0, b0};
        P1b = f32x4{b0, b0, b0, b0};

#pragma unroll 1
        for (int t = 0; t < kTH; ++t) {
            // --- phase 1: h1 (both tiles) + layer-2 partial on OLD H2 ---
#pragma unroll
            for (int r = 0; r < 4; ++r) {
                const float2 xv = *reinterpret_cast<const float2*>(
                    &xbufA[(4 * q + r) * (kTH * 2) + 2 * t]);
                Hhi1a[(4 * q + r) * kStrH + col] =
                    (_Float16)fast_tanh(fmaf(w0, xv.x, fmaf(w1, xv.y, P1a[r])));
            }
#pragma unroll
            for (int r = 0; r < 4; ++r) {
                const float2 xv = *reinterpret_cast<const float2*>(
                    &xbufB[(4 * q + r) * (kTH * 2) + 2 * t]);
                Hhi1b[(4 * q + r) * kStrH + col] =
                    (_Float16)fast_tanh(fmaf(w0, xv.x, fmaf(w1, xv.y, P1b[r])));
            }
            f32x4 a2a = {b1, b1, b1, b1};
            f32x4 a2b = {b1, b1, b1, b1};
            a2a = mfma1(H2a0, B2[0], a2a);  a2b = mfma1(H2b0, B2[0], a2b);
            a2a = mfma1(H2a1, B2[1], a2a);  a2b = mfma1(H2b1, B2[1], a2b);
            __syncthreads();   // h1' visible (both tiles)

            // --- phase 2: finish a2, produce h2' (tiles interleaved) ---
            H1a0 = read_frag(Hhi1a, aoff + q * 8);
            H1a1 = read_frag(Hhi1a, aoff + 32 + q * 8);
            H1b0 = read_frag(Hhi1b, aoff + q * 8);
            H1b1 = read_frag(Hhi1b, aoff + 32 + q * 8);
            a2a = mfma1(H1a0, B1[0], a2a);  a2b = mfma1(H1b0, B1[0], a2b);
            a2a = mfma1(H1a1, B1[1], a2a);  a2b = mfma1(H1b1, B1[1], a2b);
#pragma unroll
            for (int r = 0; r < 4; ++r)
                Hhi2a[(4 * q + r) * kStrH + col] = (_Float16)fast_tanh(a2a[r]);
#pragma unroll
            for (int r = 0; r < 4; ++r)
                Hhi2b[(4 * q + r) * kStrH + col] = (_Float16)fast_tanh(a2b[r]);
            __syncthreads();   // h2' visible (both tiles)

            // --- phase 3: next-P1 recurrent term (H1 frags still live) ---
            H2a0 = read_frag(Hhi2a, aoff + q * 8);
            H2a1 = read_frag(Hhi2a, aoff + 32 + q * 8);
            H2b0 = read_frag(Hhi2b, aoff + q * 8);
            H2b1 = read_frag(Hhi2b, aoff + 32 + q * 8);
            f32x4 npa = {b0, b0, b0, b0};
            f32x4 npb = {b0, b0, b0, b0};
            npa = mfma1(H1a0, B0[0], npa);  npb = mfma1(H1b0, B0[0], npb);
            npa = mfma1(H1a1, B0[1], npa);  npb = mfma1(H1b1, B0[1], npb);
            P1a = npa;
            P1b = npb;
        }
    }

    // ================= decoder: 80 autoregressive steps =================
    {
        const float b0 = dbih0[col] + dbhh0[col];
        const float b1 = dbih1[col] + dbhh1[col];
        const float w0 = dWih0[col * 2 + 0];
        const float w1 = dWih0[col * 2 + 1];
        const float fb0 = fcb[0];
        const float fb1 = fcb[1];
        // folded bias: feedback constant term absorbed into layer-1 bias
        const float b0p = b0 + w0 * fb0 + w1 * fb1;
        const float fbp = (p == 0) ? fb0 : fb1;   // for LDS stash from p<2 lanes
        f16x8 B0[2], B1[2], B2[2], BF[2], BG[2];
        loadB1(dWhh0, col, q, B0);
        loadB1(dWih1, col, q, B1);
        loadB1(dWhh1, col, q, B2);
        loadBfc(fcW, p, q, BF);
        loadBG(fcW, w0, w1, q, BG);   // rank-2 folded feedback matrix

        // P1 for the FIRST decoder step: b0 + Whh0.h1_enc + w0*x_last0 + w1*x_last1
        P1a = f32x4{b0, b0, b0, b0};
        P1b = f32x4{b0, b0, b0, b0};
        P1a = mfma1(H1a0, B0[0], P1a);  P1b = mfma1(H1b0, B0[0], P1b);
        P1a = mfma1(H1a1, B0[1], P1a);  P1b = mfma1(H1b1, B0[1], P1b);
#pragma unroll
        for (int r = 0; r < 4; ++r) {
            const float2 xv = *reinterpret_cast<const float2*>(
                &xbufA[(4 * q + r) * (kTH * 2) + 2 * (kTH - 1)]);
            P1a[r] = fmaf(w0, xv.x, fmaf(w1, xv.y, P1a[r]));
        }
#pragma unroll
        for (int r = 0; r < 4; ++r) {
            const float2 xv = *reinterpret_cast<const float2*>(
                &xbufB[(4 * q + r) * (kTH * 2) + 2 * (kTH - 1)]);
            P1b[r] = fmaf(w0, xv.x, fmaf(w1, xv.y, P1b[r]));
        }

#pragma unroll 1
        for (int t = 0; t < kTP; ++t) {
            // --- phase 1: h1 (both tiles) + layer-2 partial on OLD H2 ---
#pragma unroll
            for (int r = 0; r < 4; ++r)
                Hhi1a[(4 * q + r) * kStrH + col] = (_Float16)fast_tanh(P1a[r]);
#pragma unroll
            for (int r = 0; r < 4; ++r)
                Hhi1b[(4 * q + r) * kStrH + col] = (_Float16)fast_tanh(P1b[r]);
            f32x4 a2a = {b1, b1, b1, b1};
            f32x4 a2b = {b1, b1, b1, b1};
            a2a = mfma1(H2a0, B2[0], a2a);  a2b = mfma1(H2b0, B2[0], a2b);
            a2a = mfma1(H2a1, B2[1], a2a);  a2b = mfma1(H2b1, B2[1], a2b);
            __syncthreads();   // h1' visible

            // --- phase 2: finish a2, produce h2' ---
            H1a0 = read_frag(Hhi1a, aoff + q * 8);
            H1a1 = read_frag(Hhi1a, aoff + 32 + q * 8);
            H1b0 = read_frag(Hhi1b, aoff + q * 8);
            H1b1 = read_frag(Hhi1b, aoff + 32 + q * 8);
            a2a = mfma1(H1a0, B1[0], a2a);  a2b = mfma1(H1b0, B1[0], a2b);
            a2a = mfma1(H1a1, B1[1], a2a);  a2b = mfma1(H1b1, B1[1], a2b);
#pragma unroll
            for (int r = 0; r < 4; ++r)
                Hhi2a[(4 * q + r) * kStrH + col] = (_Float16)fast_tanh(a2a[r]);
#pragma unroll
            for (int r = 0; r < 4; ++r)
                Hhi2b[(4 * q + r) * kStrH + col] = (_Float16)fast_tanh(a2b[r]);
            __syncthreads();   // h2' visible

            // --- phase 3: next-P1 as two independent 2-chains per tile
            //              (G.h2 || B0.h1), merged with one vector add ---
            H2a0 = read_frag(Hhi2a, aoff + q * 8);
            H2a1 = read_frag(Hhi2a, aoff + 32 + q * 8);
            H2b0 = read_frag(Hhi2b, aoff + q * 8);
            H2b1 = read_frag(Hhi2b, aoff + 32 + q * 8);
            f32x4 nga = {b0p, b0p, b0p, b0p};
            f32x4 ngb = {b0p, b0p, b0p, b0p};
            f32x4 nba = {0.f, 0.f, 0.f, 0.f};
            f32x4 nbb = {0.f, 0.f, 0.f, 0.f};
            nga = mfma1(H2a0, BG[0], nga);  nba = mfma1(H1a0, B0[0], nba);
            ngb = mfma1(H2b0, BG[0], ngb);  nbb = mfma1(H1b0, B0[0], nbb);
            nga = mfma1(H2a1, BG[1], nga);  nba = mfma1(H1a1, B0[1], nba);
            ngb = mfma1(H2b1, BG[1], ngb);  nbb = mfma1(H1b1, B0[1], nbb);
            P1a = nga + nba;
            P1b = ngb + nbb;

            // fc: both tiles computed unconditionally on all waves (no branch
            // around MFMAs); only waves 0/1, lanes p<2 do the LDS stores.
            f32x4 fc0 = {0.f, 0.f, 0.f, 0.f};
            f32x4 fc1 = {0.f, 0.f, 0.f, 0.f};
            fc0 = mfma1(H2a0, BF[0], fc0);  fc1 = mfma1(H2b0, BF[0], fc1);
            fc0 = mfma1(H2a1, BF[1], fc0);  fc1 = mfma1(H2b1, BF[1], fc1);
            if (wv == 0 && p < 2) {
#pragma unroll
                for (int r = 0; r < 4; ++r)
                    predbuf[((4 * q + r) * kTP + t) * 2 + p] = fc0[r] + fbp;
            }
            if (wv == 1 && p < 2) {
#pragma unroll
                for (int r = 0; r < 4; ++r)
                    predbuf[kPB + ((4 * q + r) * kTP + t) * 2 + p] = fc1[r] + fbp;
            }
        }
    }

    // flush preds: block covers out[r0*kTP*2 .. (r0+32)*kTP*2), contiguous & aligned
    __syncthreads();
    {
        float4* dst = reinterpret_cast<float4*>(out + r0 * (kTP * 2));
        const float4* src = reinterpret_cast<const float4*>(predbuf);
        for (int i = tid; i < 2 * kPB / 4; i += 256)
            dst[i] = src[i];
    }
}

extern "C" void kernel_launch(void* const* d_in, const int* in_sizes, int n_in,
                              void* d_out, int out_size, void* d_ws, size_t ws_size,
                              hipStream_t stream) {
    const float* x     = (const float*)d_in[0];
    const float* eWih0 = (const float*)d_in[1];
    const float* eWhh0 = (const float*)d_in[2];
    const float* ebih0 = (const float*)d_in[3];
    const float* ebhh0 = (const float*)d_in[4];
    const float* eWih1 = (const float*)d_in[5];
    const float* eWhh1 = (const float*)d_in[6];
    const float* ebih1 = (const float*)d_in[7];
    const float* ebhh1 = (const float*)d_in[8];
    const float* dWih0 = (const float*)d_in[9];
    const float* dWhh0 = (const float*)d_in[10];
    const float* dbih0 = (const float*)d_in[11];
    const float* dbhh0 = (const float*)d_in[12];
    const float* dWih1 = (const float*)d_in[13];
    const float* dWhh1 = (const float*)d_in[14];
    const float* dbih1 = (const float*)d_in[15];
    const float* dbhh1 = (const float*)d_in[16];
    const float* fcW   = (const float*)d_in[17];
    const float* fcb   = (const float*)d_in[18];
    float* out = (float*)d_out;

    dim3 grid(kB / (2 * kM));   // 256 blocks x 4 waves; 1 block/CU, 2-tile ILP
    dim3 block(256);
    traj_rnn_kernel<<<grid, block, 0, stream>>>(
        x, eWih0, eWhh0, ebih0, ebhh0, eWih1, eWhh1, ebih1, ebhh1,
        dWih0, dWhh0, dbih0, dbhh0, dWih1, dWhh1, dbih1, dbhh1,
        fcW, fcb, out);
}